// Round 3
// baseline (1075.778 us; speedup 1.0000x reference)
//
#include <hip/hip_runtime.h>
#include <hip/hip_bf16.h>

// GNN_Bet: N=8192 nodes, H=32 hidden.
// 8 passes of skinny GEMM C[8192,32] = adj[8192,8192](fp32) @ Y[8192,32],
// fp32-class accuracy via split-bf16 (hi/lo) MFMA: A*B ~= Ah*Bh + Al*Bh + Ah*Bl.
// HBM floor: 8 x 256MB = 2GB -> ~320us at 6.3 TB/s. Everything else is noise.
// Robustness note: A and B fragments use the same (lane-group, slot)->k
// bijection, so only row/col = lane&15 and the C/D map must match HW.

typedef unsigned short u16;
typedef __bf16 bf16x8 __attribute__((ext_vector_type(8)));
typedef u16 u16x8 __attribute__((ext_vector_type(8)));
typedef float f32x4 __attribute__((ext_vector_type(4)));

#define NN 8192
#define HH 32

// RNE hi + RNE lo of the exact residual. Compiler lowers the casts to
// v_cvt_pk_bf16_f32 pairs (guide m240: don't hand-write cvt_pk).
__device__ __forceinline__ void split_bf16(float f, u16& h, u16& l) {
    __hip_bfloat16 hb = __float2bfloat16(f);
    float hf = __bfloat162float(hb);
    __hip_bfloat16 lb = __float2bfloat16(f - hf);
    h = __builtin_bit_cast(u16, hb);
    l = __builtin_bit_cast(u16, lb);
}

// ---------------------------------------------------------------------------
// Prep: packed B-fragment blob for the skinny GEMM.
// Layout: [T=256][n=2][h=2(hi/lo)][lane=64][8 bf16], 1 MB total.
// Fragment (T,n), lane L, slot j supplies Y[32T + (L>>4)*8 + j][16n + (L&15)]
// (B-operand of mfma_f32_16x16x32_bf16: col=lane&15, k=(lane>>4)*8+j).
// have_w=0: Y = X (W0, [8192][32]).  have_w=1: Y = X[8192,32] @ W[32,32].
// ---------------------------------------------------------------------------
__global__ void prep_y(const float* __restrict__ X,
                       const float* __restrict__ W,
                       u16* __restrict__ Yp,
                       const int have_w)
{
    const int gw = (blockIdx.x * blockDim.x + threadIdx.x) >> 6;  // 0..511
    const int lane = threadIdx.x & 63;
    const int t = gw >> 1, n = gw & 1;
    const int c = n * 16 + (lane & 15);
    const int k0 = t * 32 + ((lane >> 4) << 3);

    u16x8 hi, lo;
#pragma unroll
    for (int j = 0; j < 8; ++j) {
        const int k = k0 + j;
        float v;
        if (have_w) {
            v = 0.0f;
#pragma unroll
            for (int h = 0; h < 32; ++h)
                v += X[k * 32 + h] * W[h * 32 + c];
        } else {
            v = X[k * 32 + c];
        }
        u16 hb, lb;
        split_bf16(v, hb, lb);
        hi[j] = hb; lo[j] = lb;
    }
    const size_t base = ((size_t)(t * 4 + n * 2) * 64 + lane) * 8;
    *(u16x8*)(Yp + base)       = hi;
    *(u16x8*)(Yp + base + 512) = lo;
}

// ---------------------------------------------------------------------------
// Skinny GEMM: C[8192,32] = A[8192,8192](fp32) @ Y, epilogue relu(+l2norm).
// Block: 512 thr = 8 waves, M-tile = 16 rows, per-wave K-slice = 1024
// (split-K inside block, LDS reduction). 512 blocks -> 16 waves/CU for
// HBM latency hiding. A split hi/lo bf16 on the fly; 3 MFMAs/(frag,K-step).
// ---------------------------------------------------------------------------
__global__ __launch_bounds__(512, 4) void gemm_skinny(
    const float* __restrict__ A,
    const u16* __restrict__ Yp,
    float* __restrict__ Xout,
    const int do_norm)
{
    const int tid  = threadIdx.x;
    const int wave = tid >> 6;
    const int lane = tid & 63;
    const int m0   = blockIdx.x * 16;

    const int kbase = wave * 1024;
    const int row   = m0 + (lane & 15);
    const int klane = (lane >> 4) << 3;

    const float* ap = A + (size_t)row * NN + kbase + klane;
    const u16*   yp = Yp + (size_t)(kbase >> 5) * 2048 + lane * 8;

    f32x4 acc0 = {0.f, 0.f, 0.f, 0.f};
    f32x4 acc1 = {0.f, 0.f, 0.f, 0.f};

    for (int t = 0; t < 32; ++t) {
        const float4 a0 = *(const float4*)(ap);
        const float4 a1 = *(const float4*)(ap + 4);
        ap += 32;

        const float av[8] = {a0.x, a0.y, a0.z, a0.w, a1.x, a1.y, a1.z, a1.w};
        u16x8 hi, lo;
#pragma unroll
        for (int j = 0; j < 8; ++j) {
            u16 hb, lb;
            split_bf16(av[j], hb, lb);
            hi[j] = hb; lo[j] = lb;
        }
        const bf16x8 ahi = __builtin_bit_cast(bf16x8, hi);
        const bf16x8 alo = __builtin_bit_cast(bf16x8, lo);

        const bf16x8 b0h = *(const bf16x8*)(yp);
        const bf16x8 b0l = *(const bf16x8*)(yp + 512);
        const bf16x8 b1h = *(const bf16x8*)(yp + 1024);
        const bf16x8 b1l = *(const bf16x8*)(yp + 1536);
        yp += 2048;

        acc0 = __builtin_amdgcn_mfma_f32_16x16x32_bf16(ahi, b0h, acc0, 0, 0, 0);
        acc1 = __builtin_amdgcn_mfma_f32_16x16x32_bf16(ahi, b1h, acc1, 0, 0, 0);
        acc0 = __builtin_amdgcn_mfma_f32_16x16x32_bf16(alo, b0h, acc0, 0, 0, 0);
        acc1 = __builtin_amdgcn_mfma_f32_16x16x32_bf16(alo, b1h, acc1, 0, 0, 0);
        acc0 = __builtin_amdgcn_mfma_f32_16x16x32_bf16(ahi, b0l, acc0, 0, 0, 0);
        acc1 = __builtin_amdgcn_mfma_f32_16x16x32_bf16(ahi, b1l, acc1, 0, 0, 0);
    }

    // C/D layout (m89-verified): col = lane&15, row = (lane>>4)*4 + reg.
    __shared__ float cred[8][16][32];
#pragma unroll
    for (int n = 0; n < 2; ++n) {
        const f32x4 a = n ? acc1 : acc0;
#pragma unroll
        for (int r = 0; r < 4; ++r) {
            const int crow = ((lane >> 4) << 2) + r;
            const int ccol = n * 16 + (lane & 15);
            cred[wave][crow][ccol] = a[r];
        }
    }
    __syncthreads();

    // 512 outputs, 512 threads. Row r = threads r*32..r*32+31 (one 32-lane
    // half of a wave -> shfl_xor<32 reduces the row).
    {
        const int r = tid >> 5, c = tid & 31;
        float v = 0.0f;
#pragma unroll
        for (int w = 0; w < 8; ++w) v += cred[w][r][c];
        v = fmaxf(v, 0.0f);
        float outv = v;
        if (do_norm) {
            float ss = v * v;
#pragma unroll
            for (int m = 1; m < 32; m <<= 1)
                ss += __shfl_xor(ss, m, 64);
            const float inv = 1.0f / fmaxf(sqrtf(ss), 1e-12f);
            outv = v * inv;
        }
        Xout[(m0 + r) * 32 + c] = outv;
    }
}

// ---------------------------------------------------------------------------
// Scoring MLP per feature map: s = relu(relu(x@l1w+b1)@l2w+b2)@l3w+b3.
// One thread per (map, node); weights broadcast via scalar cache.
// ---------------------------------------------------------------------------
__global__ void mlp_score(const float* __restrict__ xs,
                          const float* __restrict__ l1w, const float* __restrict__ l1b,
                          const float* __restrict__ l2w, const float* __restrict__ l2b,
                          const float* __restrict__ l3w, const float* __restrict__ l3b,
                          float* __restrict__ spart)
{
    const int node = blockIdx.x * blockDim.x + threadIdx.x;
    const int map  = blockIdx.y;
    const float* x = xs + ((size_t)map * NN + node) * HH;

    float xr[32];
#pragma unroll
    for (int h = 0; h < 32; ++h) xr[h] = x[h];

    float h1[64];
#pragma unroll
    for (int f = 0; f < 64; ++f) {
        float a = l1b[f];
#pragma unroll
        for (int h = 0; h < 32; ++h) a += xr[h] * l1w[h * 64 + f];
        h1[f] = fmaxf(a, 0.0f);
    }
    float s = l3b[0];
#pragma unroll
    for (int g = 0; g < 64; ++g) {
        float a = l2b[g];
#pragma unroll
        for (int f = 0; f < 64; ++f) a += h1[f] * l2w[f * 64 + g];
        s += fmaxf(a, 0.0f) * l3w[g];
    }
    spart[(size_t)map * NN + node] = s;
}

__global__ void combine(const float* __restrict__ spart, float* __restrict__ out)
{
    const int n = blockIdx.x * blockDim.x + threadIdx.x;
    const float s1 = spart[n] + spart[NN + n] + spart[2 * NN + n] + spart[3 * NN + n];
    const float s2 = spart[4 * NN + n] + spart[5 * NN + n] + spart[6 * NN + n] + spart[7 * NN + n];
    out[n] = s1 * s2;
}

// ---------------------------------------------------------------------------
extern "C" void kernel_launch(void* const* d_in, const int* in_sizes, int n_in,
                              void* d_out, int out_size, void* d_ws, size_t ws_size,
                              hipStream_t stream)
{
    const float* adj1 = (const float*)d_in[0];
    const float* adj2 = (const float*)d_in[1];
    const float* W0   = (const float*)d_in[2];
    const float* Wl[3] = {(const float*)d_in[3], (const float*)d_in[4], (const float*)d_in[5]};
    const float* l1w = (const float*)d_in[6];
    const float* l1b = (const float*)d_in[7];
    const float* l2w = (const float*)d_in[8];
    const float* l2b = (const float*)d_in[9];
    const float* l3w = (const float*)d_in[10];
    const float* l3b = (const float*)d_in[11];
    float* out = (float*)d_out;

    char* ws = (char*)d_ws;
    u16*   Yp    = (u16*)ws;                          // 1 MB packed Y (hi/lo)
    float* xs    = (float*)(ws + (1 << 20));          // 8 maps x [8192][32] fp32 = 8 MB
    float* spart = (float*)(ws + (9 << 20));          // [8][8192] partial scores

    const size_t mapsz = (size_t)NN * HH;

    for (int br = 0; br < 2; ++br) {
        const float* adj = br ? adj2 : adj1;
        float* xb = xs + (size_t)br * 4 * mapsz;

        prep_y<<<128, 256, 0, stream>>>(W0, nullptr, Yp, 0);            // Y = W0
        gemm_skinny<<<512, 512, 0, stream>>>(adj, Yp, xb, 1);
        prep_y<<<128, 256, 0, stream>>>(xb, Wl[0], Yp, 1);              // Y = x1@W2
        gemm_skinny<<<512, 512, 0, stream>>>(adj, Yp, xb + mapsz, 1);
        prep_y<<<128, 256, 0, stream>>>(xb + mapsz, Wl[1], Yp, 1);      // Y = x2@W3
        gemm_skinny<<<512, 512, 0, stream>>>(adj, Yp, xb + 2 * mapsz, 1);
        prep_y<<<128, 256, 0, stream>>>(xb + 2 * mapsz, Wl[2], Yp, 1);  // Y = x3@W4
        gemm_skinny<<<512, 512, 0, stream>>>(adj, Yp, xb + 3 * mapsz, 0);
    }

    mlp_score<<<dim3(NN / 256, 8), 256, 0, stream>>>(xs, l1w, l1b, l2w, l2b, l3w, l3b, spart);
    combine<<<NN / 256, 256, 0, stream>>>(spart, out);
}

// Round 5
// 976.423 us; speedup vs baseline: 1.1018x; 1.1018x over previous
//
#include <hip/hip_runtime.h>
#include <hip/hip_bf16.h>

// GNN_Bet: N=8192, H=32. 8 passes of skinny GEMM C[8192,32] = adj @ Y.
// fp32-class accuracy via split-bf16 (hi/lo): A*B ~= Ah*Bh + Al*Bh + Ah*Bl.
// v4: global_load_lds fp32 staging (wave-private dbuf, no barriers),
// counted vmcnt(4) prefetch, 16B-slot XOR swizzle (both sides, rule #21).
// HBM floor: 8 x 256MB = 2GB -> ~320us at 6.3 TB/s.

typedef unsigned short u16;
typedef __bf16 bf16x8 __attribute__((ext_vector_type(8)));
typedef u16 u16x8 __attribute__((ext_vector_type(8)));
typedef float f32x4 __attribute__((ext_vector_type(4)));

#define NN 8192
#define HH 32

#define GLL16(gp, lp)                                                         \
    __builtin_amdgcn_global_load_lds(                                         \
        (const __attribute__((address_space(1))) void*)(gp),                  \
        (__attribute__((address_space(3))) void*)(lp), 16, 0, 0)

__device__ __forceinline__ void split_bf16(float f, u16& h, u16& l) {
    __hip_bfloat16 hb = __float2bfloat16(f);          // RNE hi
    float hf = __bfloat162float(hb);
    __hip_bfloat16 lb = __float2bfloat16(f - hf);     // RNE lo of exact residual
    h = __builtin_bit_cast(u16, hb);
    l = __builtin_bit_cast(u16, lb);
}

// ---------------------------------------------------------------------------
// Prep: packed B-fragment blob. Layout [T=256][n=2][h=2][lane=64][8 bf16], 1MB.
// Fragment (T,n), lane L, slot j holds Y[32T + (L>>4)*8 + j][16n + (L&15)].
// have_w=0: Y = X (W0).  have_w=1: Y = X[8192,32] @ W[32,32].
// (unchanged from the round-3 PASSED kernel)
// ---------------------------------------------------------------------------
__global__ void prep_y(const float* __restrict__ X,
                       const float* __restrict__ W,
                       u16* __restrict__ Yp,
                       const int have_w)
{
    const int gw = (blockIdx.x * blockDim.x + threadIdx.x) >> 6;  // 0..511
    const int lane = threadIdx.x & 63;
    const int t = gw >> 1, n = gw & 1;
    const int c = n * 16 + (lane & 15);
    const int k0 = t * 32 + ((lane >> 4) << 3);

    float wcol[32];
    if (have_w) {
#pragma unroll
        for (int h = 0; h < 32; ++h) wcol[h] = W[h * 32 + c];
    }

    u16x8 hi, lo;
#pragma unroll
    for (int j = 0; j < 8; ++j) {
        const int k = k0 + j;
        float v;
        if (have_w) {
            v = 0.0f;
#pragma unroll
            for (int q = 0; q < 8; ++q) {
                const float4 x4 = *(const float4*)(X + k * 32 + q * 4);
                v += x4.x * wcol[q * 4] + x4.y * wcol[q * 4 + 1]
                   + x4.z * wcol[q * 4 + 2] + x4.w * wcol[q * 4 + 3];
            }
        } else {
            v = X[k * 32 + c];
        }
        u16 hb, lb;
        split_bf16(v, hb, lb);
        hi[j] = hb; lo[j] = lb;
    }
    const size_t base = ((size_t)(t * 4 + n * 2) * 64 + lane) * 8;
    *(u16x8*)(Yp + base)       = hi;
    *(u16x8*)(Yp + base + 512) = lo;
}

// ---------------------------------------------------------------------------
// Skinny GEMM v4. 512 thr = 8 waves; M-tile 16 rows; wave w owns K-slab
// [w*1024,(w+1)*1024) as 16 sub-slabs of 64 cols (4KB fp32 each).
// Staging: 4x global_load_lds(16B) per slab into wave-private dbuf
// SAf[wave][buf][16][64]; per-lane global src address carries the
// slot-XOR-row swizzle so swizzled ds_reads are conflict-minimal (8-phase
// b128 floor). Pipeline: B-loads(s) | gll(s+1) | vmcnt(4) | compute(s).
// No __syncthreads in main loop. LDS 64KB -> 2 blocks/CU, 16 waves/CU.
// ---------------------------------------------------------------------------
__global__ __launch_bounds__(512, 4) void gemm_skinny(
    const float* __restrict__ A,
    const u16* __restrict__ Yp,
    float* __restrict__ Xout,
    const int do_norm)
{
    __shared__ float SAf[8][2][16][64];   // 65536 B

    const int tid  = threadIdx.x;
    const int wave = tid >> 6;
    const int lane = tid & 63;
    const int m0   = blockIdx.x * 16;
    const int wslab = wave * 1024;

    // staging geometry: gll inst i writes rows 4i..4i+3 linearly;
    // lane -> (subrow ls, 16B slot sl); source column swizzled: gslot = sl^row.
    const int ls = lane >> 4;
    const int sl = lane & 15;
    // fragment geometry
    const int frow = lane & 15;
    const int fg   = lane >> 4;

    const float* gp[4];
#pragma unroll
    for (int i = 0; i < 4; ++i) {
        const int row_l = 4 * i + ls;              // 0..15
        const int gs    = sl ^ row_l;              // swizzled 16B slot
        gp[i] = A + (size_t)(m0 + row_l) * NN + wslab + gs * 4;
    }

    const u16* yp = Yp + (size_t)(wave * 32) * 2048 + lane * 8;

    f32x4 acc0 = {0.f, 0.f, 0.f, 0.f};
    f32x4 acc1 = {0.f, 0.f, 0.f, 0.f};

#define ISSUE_GLL(b)                                                          \
    {                                                                         \
        _Pragma("unroll")                                                     \
        for (int i = 0; i < 4; ++i) {                                         \
            GLL16(gp[i], &SAf[wave][b][4 * i][0]);                            \
            gp[i] += 64;                                                      \
        }                                                                     \
    }

#define LOAD_B(BV)                                                            \
    bf16x8 BV[2][4];                                                          \
    {                                                                         \
        _Pragma("unroll")                                                     \
        for (int kk = 0; kk < 2; ++kk) {                                      \
            const u16* y = yp + kk * 2048;                                    \
            BV[kk][0] = *(const bf16x8*)(y);          /* b0 hi */             \
            BV[kk][1] = *(const bf16x8*)(y + 512);    /* b0 lo */             \
            BV[kk][2] = *(const bf16x8*)(y + 1024);   /* b1 hi */             \
            BV[kk][3] = *(const bf16x8*)(y + 1536);   /* b1 lo */             \
        }                                                                     \
        yp += 4096;                                                           \
    }

#define COMPUTE_SLAB(b, BV)                                                   \
    {                                                                         \
        _Pragma("unroll")                                                     \
        for (int kk = 0; kk < 2; ++kk) {                                      \
            const int p0 = kk * 8 + fg * 2;                                   \
            const f32x4 va = *(const f32x4*)&SAf[wave][b][frow][(p0 ^ frow) * 4];       \
            const f32x4 vb = *(const f32x4*)&SAf[wave][b][frow][((p0 + 1) ^ frow) * 4]; \
            const float av[8] = {va[0], va[1], va[2], va[3],                  \
                                 vb[0], vb[1], vb[2], vb[3]};                 \
            u16x8 hiu, lou;                                                   \
            _Pragma("unroll")                                                 \
            for (int j = 0; j < 8; ++j) {                                     \
                u16 hb, lb;                                                   \
                split_bf16(av[j], hb, lb);                                    \
                hiu[j] = hb; lou[j] = lb;                                     \
            }                                                                 \
            const bf16x8 ahi = __builtin_bit_cast(bf16x8, hiu);               \
            const bf16x8 alo = __builtin_bit_cast(bf16x8, lou);               \
            acc0 = __builtin_amdgcn_mfma_f32_16x16x32_bf16(ahi, BV[kk][0], acc0, 0, 0, 0); \
            acc1 = __builtin_amdgcn_mfma_f32_16x16x32_bf16(ahi, BV[kk][2], acc1, 0, 0, 0); \
            acc0 = __builtin_amdgcn_mfma_f32_16x16x32_bf16(alo, BV[kk][0], acc0, 0, 0, 0); \
            acc1 = __builtin_amdgcn_mfma_f32_16x16x32_bf16(alo, BV[kk][2], acc1, 0, 0, 0); \
            acc0 = __builtin_amdgcn_mfma_f32_16x16x32_bf16(ahi, BV[kk][1], acc0, 0, 0, 0); \
            acc1 = __builtin_amdgcn_mfma_f32_16x16x32_bf16(ahi, BV[kk][3], acc1, 0, 0, 0); \
        }                                                                     \
    }

    // prologue: stage slab 0 into buf 0
    ISSUE_GLL(0)

#pragma unroll 2
    for (int s = 0; s < 15; ++s) {
        LOAD_B(Bv)                                   // queue: gll(s)4 + B(s)8
        __builtin_amdgcn_sched_barrier(0);
        ISSUE_GLL((s + 1) & 1)                       // + gll(s+1)4 = 16
        __builtin_amdgcn_sched_barrier(0);
        asm volatile("s_waitcnt vmcnt(4)" ::: "memory");  // drain gll(s)+B(s)
        __builtin_amdgcn_sched_barrier(0);
        COMPUTE_SLAB(s & 1, Bv)
        __builtin_amdgcn_sched_barrier(0);
    }
    {   // peeled s = 15: no prefetch, full drain
        LOAD_B(Bv)
        asm volatile("s_waitcnt vmcnt(0)" ::: "memory");
        __builtin_amdgcn_sched_barrier(0);
        COMPUTE_SLAB(1, Bv)
    }
#undef ISSUE_GLL
#undef LOAD_B
#undef COMPUTE_SLAB

    // ---- cross-wave reduction; reuse SAf as cred[8][16][32] ----
    __syncthreads();
    float* cred = (float*)&SAf[0][0][0][0];
#pragma unroll
    for (int n = 0; n < 2; ++n) {
        const f32x4 a = n ? acc1 : acc0;
#pragma unroll
        for (int r = 0; r < 4; ++r) {
            // C/D layout (m89): col = lane&15, row = (lane>>4)*4 + reg
            const int crow = ((lane >> 4) << 2) + r;
            const int ccol = n * 16 + (lane & 15);
            cred[(wave * 16 + crow) * 32 + ccol] = a[r];
        }
    }
    __syncthreads();

    // 512 outputs, 512 threads; row r = threads r*32..r*32+31 (one 32-lane
    // half-wave -> shfl_xor<32 row reduce for the l2 norm)
    {
        const int r = tid >> 5, c = tid & 31;
        float v = 0.0f;
#pragma unroll
        for (int w = 0; w < 8; ++w) v += cred[(w * 16 + r) * 32 + c];
        v = fmaxf(v, 0.0f);
        float outv = v;
        if (do_norm) {
            float ss = v * v;
#pragma unroll
            for (int m = 1; m < 32; m <<= 1)
                ss += __shfl_xor(ss, m, 64);
            const float inv = 1.0f / fmaxf(sqrtf(ss), 1e-12f);
            outv = v * inv;
        }
        Xout[(m0 + r) * 32 + c] = outv;
    }
}

// ---------------------------------------------------------------------------
// Scoring MLP: s = relu(relu(x@l1w+b1)@l2w+b2)@l3w+b3, weights in LDS.
// ---------------------------------------------------------------------------
__global__ void mlp_score(const float* __restrict__ xs,
                          const float* __restrict__ l1w, const float* __restrict__ l1b,
                          const float* __restrict__ l2w, const float* __restrict__ l2b,
                          const float* __restrict__ l3w, const float* __restrict__ l3b,
                          float* __restrict__ spart)
{
    __shared__ float sw1[32 * 64], sw2[64 * 64], sw3[64], sb1[64], sb2[64];
    const int t = threadIdx.x;
    for (int i = t; i < 32 * 64; i += 256) sw1[i] = l1w[i];
    for (int i = t; i < 64 * 64; i += 256) sw2[i] = l2w[i];
    if (t < 64) { sw3[t] = l3w[t]; sb1[t] = l1b[t]; sb2[t] = l2b[t]; }
    __syncthreads();

    const int node = blockIdx.x * blockDim.x + t;
    const int map  = blockIdx.y;
    const float* x = xs + ((size_t)map * NN + node) * HH;

    float xr[32];
#pragma unroll
    for (int h = 0; h < 32; ++h) xr[h] = x[h];

    float h1[64];
#pragma unroll
    for (int f = 0; f < 64; ++f) {
        float a = sb1[f];
#pragma unroll
        for (int h = 0; h < 32; ++h) a += xr[h] * sw1[h * 64 + f];
        h1[f] = fmaxf(a, 0.0f);
    }
    float s = l3b[0];
#pragma unroll
    for (int g = 0; g < 64; ++g) {
        float a = sb2[g];
#pragma unroll
        for (int f = 0; f < 64; ++f) a += h1[f] * sw2[f * 64 + g];
        s += fmaxf(a, 0.0f) * sw3[g];
    }
    spart[(size_t)map * NN + node] = s;
}

__global__ void combine(const float* __restrict__ spart, float* __restrict__ out)
{
    const int n = blockIdx.x * blockDim.x + threadIdx.x;
    const float s1 = spart[n] + spart[NN + n] + spart[2 * NN + n] + spart[3 * NN + n];
    const float s2 = spart[4 * NN + n] + spart[5 * NN + n] + spart[6 * NN + n] + spart[7 * NN + n];
    out[n] = s1 * s2;
}

// ---------------------------------------------------------------------------
extern "C" void kernel_launch(void* const* d_in, const int* in_sizes, int n_in,
                              void* d_out, int out_size, void* d_ws, size_t ws_size,
                              hipStream_t stream)
{
    const float* adj1 = (const float*)d_in[0];
    const float* adj2 = (const float*)d_in[1];
    const float* W0   = (const float*)d_in[2];
    const float* Wl[3] = {(const float*)d_in[3], (const float*)d_in[4], (const float*)d_in[5]};
    const float* l1w = (const float*)d_in[6];
    const float* l1b = (const float*)d_in[7];
    const float* l2w = (const float*)d_in[8];
    const float* l2b = (const float*)d_in[9];
    const float* l3w = (const float*)d_in[10];
    const float* l3b = (const float*)d_in[11];
    float* out = (float*)d_out;

    char* ws = (char*)d_ws;
    u16*   Yp    = (u16*)ws;                          // 1 MB packed Y (hi/lo)
    float* xs    = (float*)(ws + (1 << 20));          // 8 x [8192][32] fp32 = 8 MB
    float* spart = (float*)(ws + (9 << 20));          // [8][8192]

    const size_t mapsz = (size_t)NN * HH;

    for (int br = 0; br < 2; ++br) {
        const float* adj = br ? adj2 : adj1;
        float* xb = xs + (size_t)br * 4 * mapsz;

        prep_y<<<128, 256, 0, stream>>>(W0, nullptr, Yp, 0);            // Y = W0
        gemm_skinny<<<512, 512, 0, stream>>>(adj, Yp, xb, 1);
        prep_y<<<128, 256, 0, stream>>>(xb, Wl[0], Yp, 1);              // Y = x1@W2
        gemm_skinny<<<512, 512, 0, stream>>>(adj, Yp, xb + mapsz, 1);
        prep_y<<<128, 256, 0, stream>>>(xb + mapsz, Wl[1], Yp, 1);      // Y = x2@W3
        gemm_skinny<<<512, 512, 0, stream>>>(adj, Yp, xb + 2 * mapsz, 1);
        prep_y<<<128, 256, 0, stream>>>(xb + 2 * mapsz, Wl[2], Yp, 1);  // Y = x3@W4
        gemm_skinny<<<512, 512, 0, stream>>>(adj, Yp, xb + 3 * mapsz, 0);
    }

    mlp_score<<<dim3(NN / 256, 8), 256, 0, stream>>>(xs, l1w, l1b, l2w, l2b, l3w, l3b, spart);
    combine<<<NN / 256, 256, 0, stream>>>(spart, out);
}